// Round 17
// baseline (285.864 us; speedup 1.0000x reference)
//
#include <hip/hip_runtime.h>
#include <cstdint>
#include <cstddef>

typedef _Float16 f16;
typedef _Float16 half8 __attribute__((ext_vector_type(8)));
typedef _Float16 half4 __attribute__((ext_vector_type(4)));
typedef float f32x4 __attribute__((ext_vector_type(4)));
typedef unsigned int u32;
typedef u32 u32x4 __attribute__((ext_vector_type(4)));

constexpr int CDIM = 192, HW = 3136, NBAT = 4, TSTEPS = 16;
constexpr int MTOT = NBAT * HW;     // 12544
constexpr int NSUB = MTOT / 16;     // 784 16-row subtiles (= recur blocks)

// ---- primary-path workspace layout (bytes) ----
constexpr size_t OFF_WX  = 0;
constexpr size_t SZ_WX   = (size_t)110592 * 2;    // 6kt*36nt*64lane*8 f16
constexpr size_t OFF_WHB = OFF_WX + SZ_WX;
constexpr size_t SZ_WHB  = (size_t)110592 * 2;    // 12nsl*3gate*6kt*64lane*8 f16
constexpr size_t OFF_U   = OFF_WHB + SZ_WHB;      // [t16][sub784][nsl12][gate3][lane64][4] f16
constexpr size_t SZ_U    = (size_t)16 * NSUB * 36 * 256 * 2;  // 231,211,008
constexpr size_t NEED    = OFF_U + SZ_U;

// ---- fallback (R5) workspace layout ----
constexpr size_t FB_WZR = 0;
constexpr size_t FB_SZ_WZR = (size_t)384*384*2;
constexpr size_t FB_WH  = FB_WZR + FB_SZ_WZR;

// =================== primary path ===================

// pack: WX in B-fragment order (k = x-half), WHB per-(nsl,gate,kt) fragments (k = h-half)
__global__ void pack_w(const float* __restrict__ wz, const float* __restrict__ wr,
                       const float* __restrict__ wh, char* __restrict__ ws) {
    int idx = blockIdx.x * 256 + threadIdx.x;   // 864*256 = 221184 exactly
    if (idx >= 221184) return;
    f16* dst;
    int lane, i, k, c, gate;
    if (idx < 110592) {
        i = idx & 7; lane = (idx >> 3) & 63;
        int ktnt = idx >> 9, kt = ktnt / 36, nt = ktnt % 36;
        int n576 = nt * 16 + (lane & 15);
        gate = n576 / 192; c = n576 % 192;
        k = kt * 32 + (lane >> 4) * 8 + i;                 // x half
        dst = (f16*)(ws + OFF_WX) + idx;
    } else {
        int j = idx - 110592;
        i = j & 7; lane = (j >> 3) & 63;
        int a = j >> 9, kt = a % 6, b = a / 6;
        gate = b % 3; int nsl = b / 3;
        c = nsl * 16 + (lane & 15);
        k = 192 + kt * 32 + (lane >> 4) * 8 + i;           // h half
        dst = (f16*)(ws + OFF_WHB) + j;
    }
    const float* W = (gate == 0) ? wz : (gate == 1) ? wr : wh;
    *dst = (f16)W[c * 384 + k];
}

// xproj: U[t][sub][nsl][gate][lane][4] = x·Wx + bias in recur fragment order (nt stores).
__global__ __launch_bounds__(512, 2) void xproj(
    const float* __restrict__ video, char* __restrict__ ws,
    const float* __restrict__ bz, const float* __restrict__ br,
    const float* __restrict__ bh) {
    __shared__ __align__(16) char AX[2][24576];  // [64][192] f16, swizzled
    const f16* WX = (const f16*)(ws + OFF_WX);
    f16* U = (f16*)(ws + OFF_U);
    const int tid = threadIdx.x, w = tid >> 6, lane = tid & 63;
    const int l15 = lane & 15, lg = lane >> 4;
    const int mt = blockIdx.x;               // 0..195
    const int bb = mt / 49, hw0 = (mt % 49) * 64;
    const int t0 = blockIdx.y * 2;
    const int mg = w >> 2, nw = w & 3;
    const int swsh = (lane & 7) << 4;
    const int slot = (l15 & 7) << 4;

#pragma unroll
    for (int p = 0; p < 2; ++p) {
        const float* vs = video + ((size_t)(bb * TSTEPS + t0 + p) * CDIM) * HW + hw0 + lane;
#pragma unroll
        for (int g = 0; g < 3; ++g) {
            half8 hv;
#pragma unroll
            for (int j = 0; j < 8; ++j)
                hv[j] = (f16)__builtin_nontemporal_load(vs + (size_t)(w * 24 + g * 8 + j) * HW);
            *(half8*)(AX[p] + lane * 384 + ((w * 48 + g * 16) ^ swsh)) = hv;
        }
    }
    float vb[9];
#pragma unroll
    for (int r = 0; r < 9; ++r) {
        int n576 = nw * 144 + r * 16 + l15;
        int gate = n576 / 192, c = n576 % 192;
        vb[r] = (gate == 0 ? bz : (gate == 1 ? br : bh))[c];
    }
    __syncthreads();

    f32x4 acc[4][9];
#pragma unroll
    for (int i = 0; i < 4; ++i)
#pragma unroll
        for (int r = 0; r < 9; ++r)
#pragma unroll
            for (int q = 0; q < 4; ++q) acc[i][r][q] = vb[r];   // bias as C-in

#pragma unroll
    for (int kt = 0; kt < 6; ++kt) {
        half8 a[4];
#pragma unroll
        for (int i = 0; i < 4; ++i)
            a[i] = *(const half8*)(AX[mg] + (i * 16 + l15) * 384 + ((kt * 64 + lg * 16) ^ slot));
#pragma unroll
        for (int r = 0; r < 9; ++r) {
            half8 bf = *(const half8*)(WX + ((size_t)(kt * 36 + nw * 9 + r) * 64 + lane) * 8);
#pragma unroll
            for (int i = 0; i < 4; ++i)
                acc[i][r] = __builtin_amdgcn_mfma_f32_16x16x32_f16(a[i], bf, acc[i][r], 0, 0, 0);
        }
    }
    const int t = t0 + mg;
#pragma unroll
    for (int r = 0; r < 9; ++r) {
        int nb = nw * 9 + r;                 // n-frag index 0..35
        int gate = nb / 12, nsl = nb % 12;
#pragma unroll
        for (int i = 0; i < 4; ++i) {
            half4 hq;
#pragma unroll
            for (int q = 0; q < 4; ++q) hq[q] = (f16)acc[i][r][q];
            int sub = mt * 4 + i;
            f16* up = U + (((size_t)t * NSUB + sub) * 36 + (size_t)nsl * 3 + gate) * 256
                        + (size_t)lane * 4;
            __builtin_nontemporal_store(hq, (half4*)up);
        }
    }
}

// recur: 784 blocks x 768 threads; block = 16 rows x full N=192 (wave wv = 16-col slice).
// THIS ROUND'S single variable: the U(t+1) loads are FORCED to issue at the top of the
// step (opaque-asm pin on the loaded values) — previously the scheduler could sink them
// to their use at the loop tail, putting ~600-900cy of L3/HBM latency on every step's
// gate phase. t-loop unroll 2 additionally lets steps' tails/heads overlap.
__global__ __attribute__((amdgpu_waves_per_eu(3, 3))) __launch_bounds__(768)
void recur(const char* __restrict__ ws, float* __restrict__ dout) {
    __shared__ __align__(16) char AH[6144], RH[6144];   // [16][192] f16, swizzled
    const f16* WHB = (const f16*)(ws + OFF_WHB);
    const f16* U = (const f16*)(ws + OFF_U);
    const int tid = threadIdx.x, wv = tid >> 6, lane = tid & 63;  // wv = nsl
    const int l15 = lane & 15, lg = lane >> 4;
    const int sub = blockIdx.x;                 // 0..783
    const int bb = sub / 196, hw0 = (sub % 196) * 16;
    const int slot = (l15 & 7) << 4;
    const int col = wv * 16 + l15;

    half8 wz_[6], wr_[6], wh_[6];
    {
        const f16* base = WHB + (size_t)wv * 9216 + lane * 8;
#pragma unroll
        for (int kt = 0; kt < 6; ++kt) {
            wz_[kt] = *(const half8*)(base + (0 * 6 + kt) * 512);
            wr_[kt] = *(const half8*)(base + (1 * 6 + kt) * 512);
            wh_[kt] = *(const half8*)(base + (2 * 6 + kt) * 512);
        }
    }
    asm volatile("" : "+v"(wz_[0]), "+v"(wz_[1]), "+v"(wz_[2]),
                      "+v"(wz_[3]), "+v"(wz_[4]), "+v"(wz_[5]));
    asm volatile("" : "+v"(wr_[0]), "+v"(wr_[1]), "+v"(wr_[2]),
                      "+v"(wr_[3]), "+v"(wr_[4]), "+v"(wr_[5]));
    asm volatile("" : "+v"(wh_[0]), "+v"(wh_[1]), "+v"(wh_[2]),
                      "+v"(wh_[3]), "+v"(wh_[4]), "+v"(wh_[5]));

    *(uint64_t*)(AH + tid * 8) = 0ull;          // h0 = 0 (swizzle-invariant)
    __syncthreads();

    int aoff[6];
#pragma unroll
    for (int kt = 0; kt < 6; ++kt) aoff[kt] = l15 * 384 + ((kt * 64 + lg * 16) ^ slot);
    int coff[4];
#pragma unroll
    for (int q = 0; q < 4; ++q) {
        int row = lg * 4 + q;
        coff[q] = row * 384 + ((2 * col) ^ ((row & 7) << 4));
    }

    const f16* ub = U + ((size_t)sub * 36 + (size_t)wv * 3) * 256 + (size_t)lane * 4;
    constexpr size_t UT = (size_t)NSUB * 36 * 256;   // f16 per t
    half4 uz = *(const half4*)(ub);
    half4 ur = *(const half4*)(ub + 256);
    half4 uh = *(const half4*)(ub + 512);

    float h_own[4] = {0.f, 0.f, 0.f, 0.f};      // own cells: (row=lg*4+q, col)
    float* ob = dout + ((size_t)(bb * TSTEPS) * CDIM + col) * HW + hw0 + lg * 4;

#pragma unroll 2
    for (int t = 0; t < TSTEPS; ++t) {
        // U(t+1) loads: pinned at this program point -> issued BEFORE phase 1, so
        // two GEMM phases + two barriers cover their L3/HBM latency.
        half4 nz = uz, nr = ur, nh = uh;
        if (t + 1 < TSTEPS) {
            const f16* un = ub + (size_t)(t + 1) * UT;
            nz = *(const half4*)(un);
            nr = *(const half4*)(un + 256);
            nh = *(const half4*)(un + 512);
            asm volatile("" : "+v"(nz), "+v"(nr), "+v"(nh));   // force issue here
        }

        // ---- phase 1: z,r GEMM (A = h from AH, B = register-resident weights) ----
        f32x4 az = {0.f, 0.f, 0.f, 0.f}, ar = {0.f, 0.f, 0.f, 0.f};
#pragma unroll
        for (int kt = 0; kt < 6; ++kt) {
            half8 a0 = *(const half8*)(AH + aoff[kt]);
            az = __builtin_amdgcn_mfma_f32_16x16x32_f16(a0, wz_[kt], az, 0, 0, 0);
            ar = __builtin_amdgcn_mfma_f32_16x16x32_f16(a0, wr_[kt], ar, 0, 0, 0);
        }
        // ---- gates: z,(1-z)h in regs; r*h -> RH (h from h_own, no LDS read) ----
        float zg[4], ho[4];
#pragma unroll
        for (int q = 0; q < 4; ++q) {
            float z = 1.f / (1.f + __expf(-(az[q] + (float)uz[q])));
            float r = 1.f / (1.f + __expf(-(ar[q] + (float)ur[q])));
            zg[q] = z; ho[q] = (1.f - z) * h_own[q];
            *(f16*)(RH + coff[q]) = (f16)(r * h_own[q]);
        }
        __syncthreads();   // B1: RH complete; all P1 AH-reads done

        // ---- phase 2: h-candidate GEMM (A = r*h) ----
        f32x4 ah = {0.f, 0.f, 0.f, 0.f};
#pragma unroll
        for (int kt = 0; kt < 6; ++kt) {
            half8 a0 = *(const half8*)(RH + aoff[kt]);
            ah = __builtin_amdgcn_mfma_f32_16x16x32_f16(a0, wh_[kt], ah, 0, 0, 0);
        }
        // ---- epilogue: h_new = (1-z)h + z*tanh -> regs + AH; dout straight from regs ----
        f32x4 hv;
#pragma unroll
        for (int q = 0; q < 4; ++q) {
            float e = __expf(2.f * (ah[q] + (float)uh[q]));
            float th = 1.f - 2.f / (e + 1.f);
            float hn = ho[q] + zg[q] * th;
            h_own[q] = hn; hv[q] = hn;
            *(f16*)(AH + coff[q]) = (f16)hn;
        }
        __builtin_nontemporal_store(hv, (f32x4*)(ob + (size_t)t * CDIM * HW));
        __syncthreads();   // B2: AH(t) complete before next-step P1 reads
        uz = nz; ur = nr; uh = nh;
    }
}

// =================== fallback path (R5, needs 442 KB ws) ===================

__global__ void pack5(const float* __restrict__ wz, const float* __restrict__ wr,
                      const float* __restrict__ wh, char* __restrict__ ws) {
    int idx = blockIdx.x * 256 + threadIdx.x;
    const int ZRT = 384 * 384;
    int n, k, NT;
    float w;
    f16* dst;
    if (idx < ZRT) {
        n = idx / 384; k = idx - n * 384;
        w = (n < 192) ? wz[n * 384 + k] : wr[(n - 192) * 384 + k];
        dst = (f16*)(ws + FB_WZR); NT = 24;
    } else {
        int j = idx - ZRT;
        if (j >= 192 * 384) return;
        n = j / 384; k = j - n * 384;
        w = wh[n * 384 + k];
        dst = (f16*)(ws + FB_WH); NT = 12;
    }
    int kt = k >> 5, g = (k >> 3) & 3, i = k & 7, nt = n >> 4;
    int lane = (g << 4) | (n & 15);
    dst[((size_t)(kt * NT + nt) * 64 + lane) * 8 + i] = (f16)w;
}

__global__ __launch_bounds__(256, 2) void gru_fb(
    const float* __restrict__ video,
    const f16* __restrict__ wZR, const f16* __restrict__ wH,
    const float* __restrict__ bz, const float* __restrict__ br,
    const float* __restrict__ bh, float* __restrict__ dout) {
    __shared__ __align__(16) char smem[73728];
    char* AX = smem;
    char* AH = smem + 24576;
    char* RH = smem + 49152;
    const int tid = threadIdx.x, w = tid >> 6, lane = tid & 63;
    const int l15 = lane & 15, lg = lane >> 4;
    const int mt = blockIdx.x, bb = mt / 49, hw0 = (mt % 49) * 64;
    const int slot = (l15 & 7) << 4;
    const int swsh = (lane & 7) << 4;
    const float* vbase = video + (size_t)bb * TSTEPS * CDIM * HW + hw0 + lane;
    float* obase = dout + (size_t)bb * TSTEPS * CDIM * HW + hw0 + lane;
    float vbz[3], vbr[3], vbh[3];
#pragma unroll
    for (int r = 0; r < 3; ++r) {
        int c = w * 48 + r * 16 + l15;
        vbz[r] = bz[c]; vbr[r] = br[c]; vbh[r] = bh[c];
    }
    {
        half8 zz = {};
#pragma unroll
        for (int i = 0; i < 6; ++i) *(half8*)(AH + tid * 96 + i * 16) = zz;
#pragma unroll
        for (int g = 0; g < 6; ++g) {
            half8 hv;
#pragma unroll
            for (int j = 0; j < 8; ++j)
                hv[j] = (f16)__builtin_nontemporal_load(vbase + (size_t)(w * 48 + g * 8 + j) * HW);
            *(half8*)(AX + lane * 384 + ((w * 96 + g * 16) ^ swsh)) = hv;
        }
    }
    __syncthreads();
#pragma unroll 1
    for (int t = 0; t < TSTEPS; ++t) {
        f32x4 az[4][3], ar[4][3];
#pragma unroll
        for (int i = 0; i < 4; ++i)
#pragma unroll
            for (int r = 0; r < 3; ++r)
#pragma unroll
                for (int q = 0; q < 4; ++q) { az[i][r][q] = 0.f; ar[i][r][q] = 0.f; }
#pragma unroll
        for (int kt = 0; kt < 12; ++kt) {
            const char* ab = (kt < 6) ? AX : AH;
            int kb = (kt % 6) * 64 + lg * 16;
            half8 a[4];
#pragma unroll
            for (int i = 0; i < 4; ++i)
                a[i] = *(const half8*)(ab + (i * 16 + l15) * 384 + (kb ^ slot));
#pragma unroll
            for (int r = 0; r < 3; ++r) {
                half8 bzf = *(const half8*)(wZR + ((size_t)(kt * 24 + w * 3 + r) * 64 + lane) * 8);
                half8 brf = *(const half8*)(wZR + ((size_t)(kt * 24 + 12 + w * 3 + r) * 64 + lane) * 8);
#pragma unroll
                for (int i = 0; i < 4; ++i)
                    az[i][r] = __builtin_amdgcn_mfma_f32_16x16x32_f16(a[i], bzf, az[i][r], 0, 0, 0);
#pragma unroll
                for (int i = 0; i < 4; ++i)
                    ar[i][r] = __builtin_amdgcn_mfma_f32_16x16x32_f16(a[i], brf, ar[i][r], 0, 0, 0);
            }
        }
        float xn[6][8];
        if (t + 1 < TSTEPS) {
            const float* vs = vbase + (size_t)(t + 1) * CDIM * HW;
#pragma unroll
            for (int g = 0; g < 6; ++g)
#pragma unroll
                for (int j = 0; j < 8; ++j)
                    xn[g][j] = __builtin_nontemporal_load(vs + (size_t)(w * 48 + g * 8 + j) * HW);
        }
#pragma unroll
        for (int i = 0; i < 4; ++i)
#pragma unroll
            for (int r = 0; r < 3; ++r)
#pragma unroll
                for (int q = 0; q < 4; ++q) {
                    int row = i * 16 + lg * 4 + q;
                    int cb2 = 2 * (w * 48 + r * 16 + l15), sw = (row & 7) << 4;
                    float rg = 1.f / (1.f + __expf(-(ar[i][r][q] + vbr[r])));
                    float hvv = (float)*(const f16*)(AH + row * 384 + (cb2 ^ sw));
                    *(f16*)(RH + row * 384 + (cb2 ^ sw)) = (f16)(rg * hvv);
                }
        __syncthreads();
        f32x4 ac[4][3];
#pragma unroll
        for (int i = 0; i < 4; ++i)
#pragma unroll
            for (int r = 0; r < 3; ++r)
#pragma unroll
                for (int q = 0; q < 4; ++q) ac[i][r][q] = 0.f;
#pragma unroll
        for (int kt = 0; kt < 12; ++kt) {
            const char* ab = (kt < 6) ? AX : RH;
            int kb = (kt % 6) * 64 + lg * 16;
            half8 a[4];
#pragma unroll
            for (int i = 0; i < 4; ++i)
                a[i] = *(const half8*)(ab + (i * 16 + l15) * 384 + (kb ^ slot));
#pragma unroll
            for (int r = 0; r < 3; ++r) {
                half8 bf = *(const half8*)(wH + ((size_t)(kt * 12 + w * 3 + r) * 64 + lane) * 8);
#pragma unroll
                for (int i = 0; i < 4; ++i)
                    ac[i][r] = __builtin_amdgcn_mfma_f32_16x16x32_f16(a[i], bf, ac[i][r], 0, 0, 0);
            }
        }
#pragma unroll
        for (int i = 0; i < 4; ++i)
#pragma unroll
            for (int r = 0; r < 3; ++r)
#pragma unroll
                for (int q = 0; q < 4; ++q) {
                    int row = i * 16 + lg * 4 + q;
                    int cb2 = 2 * (w * 48 + r * 16 + l15), sw = (row & 7) << 4;
                    float zgv = 1.f / (1.f + __expf(-(az[i][r][q] + vbz[r])));
                    float e = __expf(2.f * (ac[i][r][q] + vbh[r]));
                    float th = 1.f - 2.f / (e + 1.f);
                    float hold = (float)*(const f16*)(AH + row * 384 + (cb2 ^ sw));
                    *(f16*)(AH + row * 384 + (cb2 ^ sw)) = (f16)((1.f - zgv) * hold + zgv * th);
                }
        __syncthreads();
        {
            float* ob = obase + (size_t)t * CDIM * HW;
#pragma unroll
            for (int g = 0; g < 6; ++g) {
                half8 hv = *(const half8*)(AH + lane * 384 + ((w * 96 + g * 16) ^ swsh));
#pragma unroll
                for (int j = 0; j < 8; ++j)
                    __builtin_nontemporal_store((float)hv[j], ob + (size_t)(w * 48 + g * 8 + j) * HW);
            }
            if (t + 1 < TSTEPS) {
#pragma unroll
                for (int g = 0; g < 6; ++g) {
                    half8 o;
#pragma unroll
                    for (int j = 0; j < 8; ++j) o[j] = (f16)xn[g][j];
                    *(half8*)(AX + lane * 384 + ((w * 96 + g * 16) ^ swsh)) = o;
                }
            }
        }
        __syncthreads();
    }
}

extern "C" void kernel_launch(void* const* d_in, const int* in_sizes, int n_in,
                              void* d_out, int out_size, void* d_ws, size_t ws_size,
                              hipStream_t stream) {
    const float* video = (const float*)d_in[0];
    const float* wz = (const float*)d_in[1];
    const float* bz = (const float*)d_in[2];
    const float* wr = (const float*)d_in[3];
    const float* br = (const float*)d_in[4];
    const float* wh = (const float*)d_in[5];
    const float* bh = (const float*)d_in[6];
    char* ws = (char*)d_ws;
    float* dout = (float*)d_out;

    if (ws_size >= NEED) {
        pack_w<<<864, 256, 0, stream>>>(wz, wr, wh, ws);
        xproj<<<dim3(196, 8), 512, 0, stream>>>(video, ws, bz, br, bh);
        recur<<<NSUB, 768, 0, stream>>>(ws, dout);
    } else {
        pack5<<<864, 256, 0, stream>>>(wz, wr, wh, ws);
        gru_fb<<<196, 256, 0, stream>>>(video, (const f16*)(ws + FB_WZR),
                                        (const f16*)(ws + FB_WH), bz, br, bh, dout);
    }
}

// Round 18
// 238.224 us; speedup vs baseline: 1.2000x; 1.2000x over previous
//
#include <hip/hip_runtime.h>
#include <cstdint>
#include <cstddef>

typedef _Float16 f16;
typedef _Float16 half8 __attribute__((ext_vector_type(8)));
typedef _Float16 half4 __attribute__((ext_vector_type(4)));
typedef float f32x4 __attribute__((ext_vector_type(4)));
typedef unsigned int u32;
typedef u32 u32x4 __attribute__((ext_vector_type(4)));

constexpr int CDIM = 192, HW = 3136, NBAT = 4, TSTEPS = 16;
constexpr int MTOT = NBAT * HW;     // 12544
constexpr int NSUB = MTOT / 16;     // 784 16-row subtiles (= recur blocks)

// ---- primary-path workspace layout (bytes) ----
constexpr size_t OFF_WX  = 0;
constexpr size_t SZ_WX   = (size_t)110592 * 2;    // 6kt*36nt*64lane*8 f16
constexpr size_t OFF_WHB = OFF_WX + SZ_WX;
constexpr size_t SZ_WHB  = (size_t)110592 * 2;    // 12nsl*3gate*6kt*64lane*8 f16
constexpr size_t OFF_U   = OFF_WHB + SZ_WHB;      // [t16][sub784][nsl12][gate3][lane64][4] f16
constexpr size_t SZ_U    = (size_t)16 * NSUB * 36 * 256 * 2;  // 231,211,008
constexpr size_t NEED    = OFF_U + SZ_U;

// ---- fallback (R5) workspace layout ----
constexpr size_t FB_WZR = 0;
constexpr size_t FB_SZ_WZR = (size_t)384*384*2;
constexpr size_t FB_WH  = FB_WZR + FB_SZ_WZR;

// =================== primary path ===================

// pack: WX in B-fragment order (k = x-half), WHB per-(nsl,gate,kt) fragments (k = h-half)
__global__ void pack_w(const float* __restrict__ wz, const float* __restrict__ wr,
                       const float* __restrict__ wh, char* __restrict__ ws) {
    int idx = blockIdx.x * 256 + threadIdx.x;   // 864*256 = 221184 exactly
    if (idx >= 221184) return;
    f16* dst;
    int lane, i, k, c, gate;
    if (idx < 110592) {
        i = idx & 7; lane = (idx >> 3) & 63;
        int ktnt = idx >> 9, kt = ktnt / 36, nt = ktnt % 36;
        int n576 = nt * 16 + (lane & 15);
        gate = n576 / 192; c = n576 % 192;
        k = kt * 32 + (lane >> 4) * 8 + i;                 // x half
        dst = (f16*)(ws + OFF_WX) + idx;
    } else {
        int j = idx - 110592;
        i = j & 7; lane = (j >> 3) & 63;
        int a = j >> 9, kt = a % 6, b = a / 6;
        gate = b % 3; int nsl = b / 3;
        c = nsl * 16 + (lane & 15);
        k = 192 + kt * 32 + (lane >> 4) * 8 + i;           // h half
        dst = (f16*)(ws + OFF_WHB) + j;
    }
    const float* W = (gate == 0) ? wz : (gate == 1) ? wr : wh;
    *dst = (f16)W[c * 384 + k];
}

// xproj: U[t][sub][nsl][gate][lane][4] = x·Wx + bias in recur fragment order (nt stores).
__global__ __launch_bounds__(512, 2) void xproj(
    const float* __restrict__ video, char* __restrict__ ws,
    const float* __restrict__ bz, const float* __restrict__ br,
    const float* __restrict__ bh) {
    __shared__ __align__(16) char AX[2][24576];  // [64][192] f16, swizzled
    const f16* WX = (const f16*)(ws + OFF_WX);
    f16* U = (f16*)(ws + OFF_U);
    const int tid = threadIdx.x, w = tid >> 6, lane = tid & 63;
    const int l15 = lane & 15, lg = lane >> 4;
    const int mt = blockIdx.x;               // 0..195
    const int bb = mt / 49, hw0 = (mt % 49) * 64;
    const int t0 = blockIdx.y * 2;
    const int mg = w >> 2, nw = w & 3;
    const int swsh = (lane & 7) << 4;
    const int slot = (l15 & 7) << 4;

#pragma unroll
    for (int p = 0; p < 2; ++p) {
        const float* vs = video + ((size_t)(bb * TSTEPS + t0 + p) * CDIM) * HW + hw0 + lane;
#pragma unroll
        for (int g = 0; g < 3; ++g) {
            half8 hv;
#pragma unroll
            for (int j = 0; j < 8; ++j)
                hv[j] = (f16)__builtin_nontemporal_load(vs + (size_t)(w * 24 + g * 8 + j) * HW);
            *(half8*)(AX[p] + lane * 384 + ((w * 48 + g * 16) ^ swsh)) = hv;
        }
    }
    float vb[9];
#pragma unroll
    for (int r = 0; r < 9; ++r) {
        int n576 = nw * 144 + r * 16 + l15;
        int gate = n576 / 192, c = n576 % 192;
        vb[r] = (gate == 0 ? bz : (gate == 1 ? br : bh))[c];
    }
    __syncthreads();

    f32x4 acc[4][9];
#pragma unroll
    for (int i = 0; i < 4; ++i)
#pragma unroll
        for (int r = 0; r < 9; ++r)
#pragma unroll
            for (int q = 0; q < 4; ++q) acc[i][r][q] = vb[r];   // bias as C-in

#pragma unroll
    for (int kt = 0; kt < 6; ++kt) {
        half8 a[4];
#pragma unroll
        for (int i = 0; i < 4; ++i)
            a[i] = *(const half8*)(AX[mg] + (i * 16 + l15) * 384 + ((kt * 64 + lg * 16) ^ slot));
#pragma unroll
        for (int r = 0; r < 9; ++r) {
            half8 bf = *(const half8*)(WX + ((size_t)(kt * 36 + nw * 9 + r) * 64 + lane) * 8);
#pragma unroll
            for (int i = 0; i < 4; ++i)
                acc[i][r] = __builtin_amdgcn_mfma_f32_16x16x32_f16(a[i], bf, acc[i][r], 0, 0, 0);
        }
    }
    const int t = t0 + mg;
#pragma unroll
    for (int r = 0; r < 9; ++r) {
        int nb = nw * 9 + r;                 // n-frag index 0..35
        int gate = nb / 12, nsl = nb % 12;
#pragma unroll
        for (int i = 0; i < 4; ++i) {
            half4 hq;
#pragma unroll
            for (int q = 0; q < 4; ++q) hq[q] = (f16)acc[i][r][q];
            int sub = mt * 4 + i;
            f16* up = U + (((size_t)t * NSUB + sub) * 36 + (size_t)nsl * 3 + gate) * 256
                        + (size_t)lane * 4;
            __builtin_nontemporal_store(hq, (half4*)up);
        }
    }
}

// recur: R11-exact (best measured: 141 us). 784 blocks x 768 threads; block = 16 rows x
// full N=192 (wave wv = 16-col slice). h cells in regs (h_own); plain __syncthreads;
// U(t+1) prefetch issued after B1 (overlaps phase 2); dout straight from epilogue regs.
__global__ __launch_bounds__(768, 3) void recur(const char* __restrict__ ws,
                                                float* __restrict__ dout) {
    __shared__ __align__(16) char AH[6144], RH[6144];   // [16][192] f16, swizzled
    const f16* WHB = (const f16*)(ws + OFF_WHB);
    const f16* U = (const f16*)(ws + OFF_U);
    const int tid = threadIdx.x, wv = tid >> 6, lane = tid & 63;  // wv = nsl
    const int l15 = lane & 15, lg = lane >> 4;
    const int sub = blockIdx.x;                 // 0..783
    const int bb = sub / 196, hw0 = (sub % 196) * 16;
    const int slot = (l15 & 7) << 4;
    const int col = wv * 16 + l15;

    half8 wz_[6], wr_[6], wh_[6];
    {
        const f16* base = WHB + (size_t)wv * 9216 + lane * 8;
#pragma unroll
        for (int kt = 0; kt < 6; ++kt) {
            wz_[kt] = *(const half8*)(base + (0 * 6 + kt) * 512);
            wr_[kt] = *(const half8*)(base + (1 * 6 + kt) * 512);
            wh_[kt] = *(const half8*)(base + (2 * 6 + kt) * 512);
        }
    }
    *(uint64_t*)(AH + tid * 8) = 0ull;          // h0 = 0 (swizzle-invariant)
    __syncthreads();

    int aoff[6];
#pragma unroll
    for (int kt = 0; kt < 6; ++kt) aoff[kt] = l15 * 384 + ((kt * 64 + lg * 16) ^ slot);
    int coff[4];
#pragma unroll
    for (int q = 0; q < 4; ++q) {
        int row = lg * 4 + q;
        coff[q] = row * 384 + ((2 * col) ^ ((row & 7) << 4));
    }

    const f16* ub = U + ((size_t)sub * 36 + (size_t)wv * 3) * 256 + (size_t)lane * 4;
    constexpr size_t UT = (size_t)NSUB * 36 * 256;   // f16 per t
    half4 uz = *(const half4*)(ub);
    half4 ur = *(const half4*)(ub + 256);
    half4 uh = *(const half4*)(ub + 512);

    float h_own[4] = {0.f, 0.f, 0.f, 0.f};      // own cells: (row=lg*4+q, col)
    float* ob = dout + ((size_t)(bb * TSTEPS) * CDIM + col) * HW + hw0 + lg * 4;

#pragma unroll 1
    for (int t = 0; t < TSTEPS; ++t) {
        // ---- phase 1: z,r GEMM (A = h from AH, B = regs) ----
        f32x4 az = {0.f, 0.f, 0.f, 0.f}, ar = {0.f, 0.f, 0.f, 0.f};
#pragma unroll
        for (int kt = 0; kt < 6; ++kt) {
            half8 a0 = *(const half8*)(AH + aoff[kt]);
            az = __builtin_amdgcn_mfma_f32_16x16x32_f16(a0, wz_[kt], az, 0, 0, 0);
            ar = __builtin_amdgcn_mfma_f32_16x16x32_f16(a0, wr_[kt], ar, 0, 0, 0);
        }
        // ---- gates: z,(1-z)h in regs; r*h -> RH (h from h_own, no LDS read) ----
        float zg[4], ho[4];
#pragma unroll
        for (int q = 0; q < 4; ++q) {
            float z = 1.f / (1.f + __expf(-(az[q] + (float)uz[q])));
            float r = 1.f / (1.f + __expf(-(ar[q] + (float)ur[q])));
            zg[q] = z; ho[q] = (1.f - z) * h_own[q];
            *(f16*)(RH + coff[q]) = (f16)(r * h_own[q]);
        }
        __syncthreads();   // B1: RH complete; all P1 AH-reads done

        // prefetch U(t+1) — overlaps phase 2
        half4 nz = uz, nr = ur, nh = uh;
        if (t + 1 < TSTEPS) {
            const f16* un = ub + (size_t)(t + 1) * UT;
            nz = *(const half4*)(un);
            nr = *(const half4*)(un + 256);
            nh = *(const half4*)(un + 512);
        }

        // ---- phase 2: h-candidate GEMM (A = r*h) ----
        f32x4 ah = {0.f, 0.f, 0.f, 0.f};
#pragma unroll
        for (int kt = 0; kt < 6; ++kt) {
            half8 a0 = *(const half8*)(RH + aoff[kt]);
            ah = __builtin_amdgcn_mfma_f32_16x16x32_f16(a0, wh_[kt], ah, 0, 0, 0);
        }
        // ---- epilogue: h_new = (1-z)h + z*tanh -> regs + AH; dout straight from regs ----
        f32x4 hv;
#pragma unroll
        for (int q = 0; q < 4; ++q) {
            float e = __expf(2.f * (ah[q] + (float)uh[q]));
            float th = 1.f - 2.f / (e + 1.f);
            float hn = ho[q] + zg[q] * th;
            h_own[q] = hn; hv[q] = hn;
            *(f16*)(AH + coff[q]) = (f16)hn;
        }
        __builtin_nontemporal_store(hv, (f32x4*)(ob + (size_t)t * CDIM * HW));
        __syncthreads();   // B2: AH(t) complete before next-step P1 reads
        uz = nz; ur = nr; uh = nh;
    }
}

// =================== fallback path (R5, needs 442 KB ws) ===================

__global__ void pack5(const float* __restrict__ wz, const float* __restrict__ wr,
                      const float* __restrict__ wh, char* __restrict__ ws) {
    int idx = blockIdx.x * 256 + threadIdx.x;
    const int ZRT = 384 * 384;
    int n, k, NT;
    float w;
    f16* dst;
    if (idx < ZRT) {
        n = idx / 384; k = idx - n * 384;
        w = (n < 192) ? wz[n * 384 + k] : wr[(n - 192) * 384 + k];
        dst = (f16*)(ws + FB_WZR); NT = 24;
    } else {
        int j = idx - ZRT;
        if (j >= 192 * 384) return;
        n = j / 384; k = j - n * 384;
        w = wh[n * 384 + k];
        dst = (f16*)(ws + FB_WH); NT = 12;
    }
    int kt = k >> 5, g = (k >> 3) & 3, i = k & 7, nt = n >> 4;
    int lane = (g << 4) | (n & 15);
    dst[((size_t)(kt * NT + nt) * 64 + lane) * 8 + i] = (f16)w;
}

__global__ __launch_bounds__(256, 2) void gru_fb(
    const float* __restrict__ video,
    const f16* __restrict__ wZR, const f16* __restrict__ wH,
    const float* __restrict__ bz, const float* __restrict__ br,
    const float* __restrict__ bh, float* __restrict__ dout) {
    __shared__ __align__(16) char smem[73728];
    char* AX = smem;
    char* AH = smem + 24576;
    char* RH = smem + 49152;
    const int tid = threadIdx.x, w = tid >> 6, lane = tid & 63;
    const int l15 = lane & 15, lg = lane >> 4;
    const int mt = blockIdx.x, bb = mt / 49, hw0 = (mt % 49) * 64;
    const int slot = (l15 & 7) << 4;
    const int swsh = (lane & 7) << 4;
    const float* vbase = video + (size_t)bb * TSTEPS * CDIM * HW + hw0 + lane;
    float* obase = dout + (size_t)bb * TSTEPS * CDIM * HW + hw0 + lane;
    float vbz[3], vbr[3], vbh[3];
#pragma unroll
    for (int r = 0; r < 3; ++r) {
        int c = w * 48 + r * 16 + l15;
        vbz[r] = bz[c]; vbr[r] = br[c]; vbh[r] = bh[c];
    }
    {
        half8 zz = {};
#pragma unroll
        for (int i = 0; i < 6; ++i) *(half8*)(AH + tid * 96 + i * 16) = zz;
#pragma unroll
        for (int g = 0; g < 6; ++g) {
            half8 hv;
#pragma unroll
            for (int j = 0; j < 8; ++j)
                hv[j] = (f16)__builtin_nontemporal_load(vbase + (size_t)(w * 48 + g * 8 + j) * HW);
            *(half8*)(AX + lane * 384 + ((w * 96 + g * 16) ^ swsh)) = hv;
        }
    }
    __syncthreads();
#pragma unroll 1
    for (int t = 0; t < TSTEPS; ++t) {
        f32x4 az[4][3], ar[4][3];
#pragma unroll
        for (int i = 0; i < 4; ++i)
#pragma unroll
            for (int r = 0; r < 3; ++r)
#pragma unroll
                for (int q = 0; q < 4; ++q) { az[i][r][q] = 0.f; ar[i][r][q] = 0.f; }
#pragma unroll
        for (int kt = 0; kt < 12; ++kt) {
            const char* ab = (kt < 6) ? AX : AH;
            int kb = (kt % 6) * 64 + lg * 16;
            half8 a[4];
#pragma unroll
            for (int i = 0; i < 4; ++i)
                a[i] = *(const half8*)(ab + (i * 16 + l15) * 384 + (kb ^ slot));
#pragma unroll
            for (int r = 0; r < 3; ++r) {
                half8 bzf = *(const half8*)(wZR + ((size_t)(kt * 24 + w * 3 + r) * 64 + lane) * 8);
                half8 brf = *(const half8*)(wZR + ((size_t)(kt * 24 + 12 + w * 3 + r) * 64 + lane) * 8);
#pragma unroll
                for (int i = 0; i < 4; ++i)
                    az[i][r] = __builtin_amdgcn_mfma_f32_16x16x32_f16(a[i], bzf, az[i][r], 0, 0, 0);
#pragma unroll
                for (int i = 0; i < 4; ++i)
                    ar[i][r] = __builtin_amdgcn_mfma_f32_16x16x32_f16(a[i], brf, ar[i][r], 0, 0, 0);
            }
        }
        float xn[6][8];
        if (t + 1 < TSTEPS) {
            const float* vs = vbase + (size_t)(t + 1) * CDIM * HW;
#pragma unroll
            for (int g = 0; g < 6; ++g)
#pragma unroll
                for (int j = 0; j < 8; ++j)
                    xn[g][j] = __builtin_nontemporal_load(vs + (size_t)(w * 48 + g * 8 + j) * HW);
        }
#pragma unroll
        for (int i = 0; i < 4; ++i)
#pragma unroll
            for (int r = 0; r < 3; ++r)
#pragma unroll
                for (int q = 0; q < 4; ++q) {
                    int row = i * 16 + lg * 4 + q;
                    int cb2 = 2 * (w * 48 + r * 16 + l15), sw = (row & 7) << 4;
                    float rg = 1.f / (1.f + __expf(-(ar[i][r][q] + vbr[r])));
                    float hvv = (float)*(const f16*)(AH + row * 384 + (cb2 ^ sw));
                    *(f16*)(RH + row * 384 + (cb2 ^ sw)) = (f16)(rg * hvv);
                }
        __syncthreads();
        f32x4 ac[4][3];
#pragma unroll
        for (int i = 0; i < 4; ++i)
#pragma unroll
            for (int r = 0; r < 3; ++r)
#pragma unroll
                for (int q = 0; q < 4; ++q) ac[i][r][q] = 0.f;
#pragma unroll
        for (int kt = 0; kt < 12; ++kt) {
            const char* ab = (kt < 6) ? AX : RH;
            int kb = (kt % 6) * 64 + lg * 16;
            half8 a[4];
#pragma unroll
            for (int i = 0; i < 4; ++i)
                a[i] = *(const half8*)(ab + (i * 16 + l15) * 384 + (kb ^ slot));
#pragma unroll
            for (int r = 0; r < 3; ++r) {
                half8 bf = *(const half8*)(wH + ((size_t)(kt * 12 + w * 3 + r) * 64 + lane) * 8);
#pragma unroll
                for (int i = 0; i < 4; ++i)
                    ac[i][r] = __builtin_amdgcn_mfma_f32_16x16x32_f16(a[i], bf, ac[i][r], 0, 0, 0);
            }
        }
#pragma unroll
        for (int i = 0; i < 4; ++i)
#pragma unroll
            for (int r = 0; r < 3; ++r)
#pragma unroll
                for (int q = 0; q < 4; ++q) {
                    int row = i * 16 + lg * 4 + q;
                    int cb2 = 2 * (w * 48 + r * 16 + l15), sw = (row & 7) << 4;
                    float zgv = 1.f / (1.f + __expf(-(az[i][r][q] + vbz[r])));
                    float e = __expf(2.f * (ac[i][r][q] + vbh[r]));
                    float th = 1.f - 2.f / (e + 1.f);
                    float hold = (float)*(const f16*)(AH + row * 384 + (cb2 ^ sw));
                    *(f16*)(AH + row * 384 + (cb2 ^ sw)) = (f16)((1.f - zgv) * hold + zgv * th);
                }
        __syncthreads();
        {
            float* ob = obase + (size_t)t * CDIM * HW;
#pragma unroll
            for (int g = 0; g < 6; ++g) {
                half8 hv = *(const half8*)(AH + lane * 384 + ((w * 96 + g * 16) ^ swsh));
#pragma unroll
                for (int j = 0; j < 8; ++j)
                    __builtin_nontemporal_store((float)hv[j], ob + (size_t)(w * 48 + g * 8 + j) * HW);
            }
            if (t + 1 < TSTEPS) {
#pragma unroll
                for (int g = 0; g < 6; ++g) {
                    half8 o;
#pragma unroll
                    for (int j = 0; j < 8; ++j) o[j] = (f16)xn[g][j];
                    *(half8*)(AX + lane * 384 + ((w * 96 + g * 16) ^ swsh)) = o;
                }
            }
        }
        __syncthreads();
    }
}

extern "C" void kernel_launch(void* const* d_in, const int* in_sizes, int n_in,
                              void* d_out, int out_size, void* d_ws, size_t ws_size,
                              hipStream_t stream) {
    const float* video = (const float*)d_in[0];
    const float* wz = (const float*)d_in[1];
    const float* bz = (const float*)d_in[2];
    const float* wr = (const float*)d_in[3];
    const float* br = (const float*)d_in[4];
    const float* wh = (const float*)d_in[5];
    const float* bh = (const float*)d_in[6];
    char* ws = (char*)d_ws;
    float* dout = (float*)d_out;

    if (ws_size >= NEED) {
        pack_w<<<864, 256, 0, stream>>>(wz, wr, wh, ws);
        xproj<<<dim3(196, 8), 512, 0, stream>>>(video, ws, bz, br, bh);
        recur<<<NSUB, 768, 0, stream>>>(ws, dout);
    } else {
        pack5<<<864, 256, 0, stream>>>(wz, wr, wh, ws);
        gru_fb<<<196, 256, 0, stream>>>(video, (const f16*)(ws + FB_WZR),
                                        (const f16*)(ws + FB_WH), bz, br, bh, dout);
    }
}